// Round 12
// baseline (144.367 us; speedup 1.0000x reference)
//
#include <hip/hip_runtime.h>
#include <hip/hip_bf16.h>

#define WW 20
#define NW 8192         // 64*128 words
#define VOCAB 256
#define EE 64
#define HH 256
#define K3 768          // 3*HH
#define UNITF 2304      // f32 per vocab unit (P5f) = 9216 B

typedef short bf16x8 __attribute__((ext_vector_type(8)));
typedef float f32x4  __attribute__((ext_vector_type(4)));

__device__ __forceinline__ ushort f2bs(float x) {
    __hip_bfloat16 h = __float2bfloat16(x);
    union { __hip_bfloat16 h; ushort u; } c; c.h = h; return c.u;
}
__device__ __forceinline__ unsigned pack2(float lo, float hi) {
    return (unsigned)f2bs(lo) | ((unsigned)f2bs(hi) << 16);
}

// sliding-window update for one h given this char's 9 f32 taps (qa = taps0-3,
// qb = taps4-7, t8v = tap8). j compile-time (fully unrolled caller).
#define STEPF(j, qa, qb, t8v, a3, a5, mm1, mm3, mm5) {                   \
    mm1 = fmaxf(mm1, (qa).x);                                            \
    if ((j) + 1 < WW) a3[((j)+1)%3] = (qa).y;                            \
    a3[(j)%3] += (qa).z;                                                 \
    if ((j) >= 1) { a3[((j)-1)%3] += (qa).w;                             \
                    mm3 = fmaxf(mm3, a3[((j)-1)%3]); }                   \
    if ((j) + 2 < WW) a5[((j)+2)%5] = (qb).x;                            \
    if ((j) + 1 < WW) a5[((j)+1)%5] += (qb).y;                           \
    a5[(j)%5] += (qb).z;                                                 \
    if ((j) >= 1) a5[((j)-1)%5] += (qb).w;                               \
    if ((j) >= 2) { a5[((j)-2)%5] += (t8v);                              \
                    mm5 = fmaxf(mm5, a5[((j)-2)%5]); }                   \
}

// ---------------------------------------------------------------------------
// P5f layout (per vocab v, 2304 f32 = 9216 B): 64 slices s of 144 B:
//   [hl 0..3][taps 0..7] (4 x 32 B rows), then [tap8 for hl 0..3] (16 B).
//   j = s*36 + r;  r<32: tap=r&7, h=s*4+(r>>3);  r>=32: tap=8, h=s*4+(r-32).
// f32 taps: conv threads need NO bf16 unpack VALU (was ~8 insts/h-char).
// ---------------------------------------------------------------------------

// K0: prep. blocks 0..575: wTp[e][j] f32 (P5f column order);
//          blocks 576..767: lw f32 -> bf16.
__global__ __launch_bounds__(256) void prep(
        const float* __restrict__ w1,
        const float* __restrict__ w3,
        const float* __restrict__ w5,
        const float* __restrict__ lw,
        float* __restrict__ wTp,
        ushort* __restrict__ lwb) {
    const int bid = blockIdx.x;
    if (bid < 576) {
        int idx = bid * 256 + threadIdx.x;      // = e*2304 + j, 147456 total
        int e = idx / UNITF;
        int j = idx - e * UNITF;
        int s = j / 36, r = j - s * 36;
        int tap, h;
        if (r < 32) { tap = r & 7; h = s*4 + (r >> 3); }
        else        { tap = 8;     h = s*4 + (r - 32); }
        float v;
        if (tap == 0)      v = w1[h*EE + e];
        else if (tap <= 3) v = w3[(h*EE + e)*3 + (tap-1)];
        else               v = w5[(h*EE + e)*5 + (tap-4)];
        wTp[idx] = v;
    } else {
        int i = ((bid - 576) * 256 + threadIdx.x) * 4;
        float4 v = *(const float4*)(lw + i);
        ushort4 o4;
        o4.x = f2bs(v.x); o4.y = f2bs(v.y); o4.z = f2bs(v.z); o4.w = f2bs(v.w);
        *(ushort4*)(lwb + i) = o4;
    }
}

// K1: P5f[v][j] = sum_e emb[v][e] * wTp[e][j]. 4 vocab rows per block,
// grid (64, 9) x 256 thr. Coalesced streaming reads/writes. f32 output.
__global__ __launch_bounds__(256) void build_tables(
        const float* __restrict__ emb,
        const float* __restrict__ wTp,
        float* __restrict__ P5f) {
    __shared__ float emb_s[4][EE];
    const int v0 = blockIdx.x * 4;
    const int j  = blockIdx.y * 256 + threadIdx.x;
    const int t  = threadIdx.x;
    emb_s[t >> 6][t & 63] = emb[v0*EE + t];
    __syncthreads();

    float a0 = 0.f, a1 = 0.f, a2 = 0.f, a3 = 0.f;
    const float* wp = wTp + j;
    #pragma unroll 8
    for (int e = 0; e < EE; ++e) {
        float w = wp[e * UNITF];
        a0 += emb_s[0][e] * w; a1 += emb_s[1][e] * w;
        a2 += emb_s[2][e] * w; a3 += emb_s[3][e] * w;
    }
    P5f[(size_t)(v0+0)*UNITF + j] = a0;
    P5f[(size_t)(v0+1)*UNITF + j] = a1;
    P5f[(size_t)(v0+2)*UNITF + j] = a2;
    P5f[(size_t)(v0+3)*UNITF + j] = a3;
}

// ---------------------------------------------------------------------------
// K2: conv+relu+maxpool, LDS-staged f32 table. Block = (128 words, 4-h slice),
// grid (64, 64). Thread = (word-lane wl=t>>1, h-pair p=t&1): owns h0=s*4+2p,
// h0+1. LDS = table slice only (256 v x 144 B = 36.9 KB -> 4 blocks/CU; R11's
// chars stage dropped -- each thread loads its word's 20 chars as 5 aligned
// int4 from global/L2). Per char: 4 x ds_read_b128 + 1 x ds_read_b64, zero
// unpack VALU (f32 taps). ~54 cyc LDS vs ~50 VALU per wave-char: balanced.
// Bias after max; ReLU at the end; packed u32 stores (h0 even).
// ---------------------------------------------------------------------------
__global__ __launch_bounds__(256) void conv_pool(
        const int* __restrict__ chars,
        const float* __restrict__ P5f,
        const float* __restrict__ b1,
        const float* __restrict__ b3,
        const float* __restrict__ b5,
        ushort* __restrict__ outs) {
    __shared__ uint4 tileq[2304];          // 36864 B table slice (f32)
    const int t = threadIdx.x;
    const int g = blockIdx.x;              // word group 0..63
    const int s = blockIdx.y;              // h slice   0..63

    {   // stage table slice: 2304 16-B chunks, 9 per thread (v = c/9, k = c%9)
        const char* src = (const char*)(P5f + s * 36);
        char* dst = (char*)tileq;
        #pragma unroll
        for (int i = 0; i < 9; ++i) {
            int c = i*256 + t;
            int v = c / 9, k = c - 9*v;
            *(uint4*)(dst + v*144 + k*16) =
                *(const uint4*)(src + (size_t)v*9216 + k*16);
        }
    }

    const int p  = t & 1;                  // h pair 0..1
    const int wl = t >> 1;                 // word lane 0..127
    const int n  = g*128 + wl;
    const int h0 = s*4 + p*2;

    // this word's chars: 5 aligned int4 (n*80 B, 80 = 16*5)
    int cw[WW];
    {
        const int4* cp = (const int4*)(chars + n * WW);
        #pragma unroll
        for (int i = 0; i < 5; ++i) {
            int4 v = cp[i];
            cw[i*4+0] = v.x; cw[i*4+1] = v.y; cw[i*4+2] = v.z; cw[i*4+3] = v.w;
        }
    }

    const float2 bb1 = *(const float2*)(b1 + h0);
    const float2 bb3 = *(const float2*)(b3 + h0);
    const float2 bb5 = *(const float2*)(b5 + h0);

    __syncthreads();
    const char* tile = (const char*)tileq;

    float a3[2][3], a5[2][5], m1[2], m3[2], m5[2];
    #pragma unroll
    for (int i = 0; i < 2; ++i) {
        a3[i][0] = 0.f; a5[i][0] = 0.f; a5[i][1] = 0.f;
        m1[i] = -1e30f; m3[i] = -1e30f; m5[i] = -1e30f;
    }

    float4 qa0[2], qa1[2], qb0[2], qb1[2]; float2 t8[2];
    {   // preload char 0
        const char* pc = tile + cw[0]*144 + p*64;
        qa0[0] = *(const float4*)(pc);
        qa1[0] = *(const float4*)(pc + 16);
        qb0[0] = *(const float4*)(pc + 32);
        qb1[0] = *(const float4*)(pc + 48);
        t8[0]  = *(const float2*)(tile + cw[0]*144 + 128 + p*8);
    }

    #pragma unroll
    for (int j = 0; j < WW; ++j) {
        const int cur = j & 1, nxt = cur ^ 1;
        if (j + 1 < WW) {                  // prefetch char j+1
            const char* pc = tile + cw[j+1]*144 + p*64;
            qa0[nxt] = *(const float4*)(pc);
            qa1[nxt] = *(const float4*)(pc + 16);
            qb0[nxt] = *(const float4*)(pc + 32);
            qb1[nxt] = *(const float4*)(pc + 48);
            t8[nxt]  = *(const float2*)(tile + cw[j+1]*144 + 128 + p*8);
        }
        STEPF(j, qa0[cur], qa1[cur], t8[cur].x, a3[0], a5[0], m1[0], m3[0], m5[0]);
        STEPF(j, qb0[cur], qb1[cur], t8[cur].y, a3[1], a5[1], m1[1], m3[1], m5[1]);
    }
    #pragma unroll
    for (int i = 0; i < 2; ++i) {
        m3[i] = fmaxf(m3[i], a3[i][(WW-1)%3]);     // pos 19
        m5[i] = fmaxf(m5[i], a5[i][(WW-2)%5]);     // pos 18
        m5[i] = fmaxf(m5[i], a5[i][(WW-1)%5]);     // pos 19
    }

    unsigned* op = (unsigned*)(outs + (size_t)n * K3 + h0);
    op[0*(HH/2)] = pack2(fmaxf(m1[0]+bb1.x, 0.f), fmaxf(m1[1]+bb1.y, 0.f));
    op[1*(HH/2)] = pack2(fmaxf(m3[0]+bb3.x, 0.f), fmaxf(m3[1]+bb3.y, 0.f));
    op[2*(HH/2)] = pack2(fmaxf(m5[0]+bb5.x, 0.f), fmaxf(m5[1]+bb5.y, 0.f));
}

// ---------------------------------------------------------------------------
// K3: out = outs @ lw^T + lb via MFMA 16x16x32. 32m x 32n per wave,
// grid (256, 8) = 2048 single-wave blocks. Double-buffered fragments,
// fully unrolled K.
// A[m][k]: m=lane&15, k=quad*8+j. B[k][n]=lw[n][k]: n=lane&15, k=quad*8+j.
// C/D: col=lane&15, row=quad*4+reg.
// ---------------------------------------------------------------------------
__global__ __launch_bounds__(64) void gemm_out(
        const ushort* __restrict__ outs,   // [8192][768] bf16
        const ushort* __restrict__ lwb,    // [256][768] bf16
        const float* __restrict__ lb,
        float* __restrict__ out) {
    const int lane = threadIdx.x;
    const int m0 = blockIdx.x * 32;
    const int n0 = blockIdx.y * 32;
    const int mrow = lane & 15, quad = lane >> 4;

    f32x4 acc00 = (f32x4){0,0,0,0}, acc01 = (f32x4){0,0,0,0};
    f32x4 acc10 = (f32x4){0,0,0,0}, acc11 = (f32x4){0,0,0,0};
    const ushort* ap = outs + (size_t)(m0 + mrow) * K3 + quad * 8;
    const ushort* bp = lwb  + (size_t)(n0 + mrow) * K3 + quad * 8;

    bf16x8 a0 = *(const bf16x8*)ap, a1 = *(const bf16x8*)(ap + 16*K3);
    bf16x8 b0 = *(const bf16x8*)bp, b1 = *(const bf16x8*)(bp + 16*K3);

    #pragma unroll
    for (int it = 0; it < K3/32; ++it) {
        const int kn = (it + 1 < K3/32) ? (it + 1) * 32 : 0;
        bf16x8 a0n = *(const bf16x8*)(ap + kn);
        bf16x8 a1n = *(const bf16x8*)(ap + 16*K3 + kn);
        bf16x8 b0n = *(const bf16x8*)(bp + kn);
        bf16x8 b1n = *(const bf16x8*)(bp + 16*K3 + kn);
        acc00 = __builtin_amdgcn_mfma_f32_16x16x32_bf16(a0, b0, acc00, 0, 0, 0);
        acc01 = __builtin_amdgcn_mfma_f32_16x16x32_bf16(a0, b1, acc01, 0, 0, 0);
        acc10 = __builtin_amdgcn_mfma_f32_16x16x32_bf16(a1, b0, acc10, 0, 0, 0);
        acc11 = __builtin_amdgcn_mfma_f32_16x16x32_bf16(a1, b1, acc11, 0, 0, 0);
        a0 = a0n; a1 = a1n; b0 = b0n; b1 = b1n;
    }

    #pragma unroll
    for (int i = 0; i < 2; ++i) {
        #pragma unroll
        for (int jn = 0; jn < 2; ++jn) {
            const f32x4 acc = (i==0) ? (jn==0 ? acc00 : acc01)
                                     : (jn==0 ? acc10 : acc11);
            int ncol = n0 + jn*16 + mrow;
            float lbv = lb[ncol];
            #pragma unroll
            for (int r = 0; r < 4; ++r)
                out[(size_t)(m0 + i*16 + quad*4 + r)*HH + ncol] = acc[r] + lbv;
        }
    }
}

// ---------------------------------------------------------------------------
extern "C" void kernel_launch(void* const* d_in, const int* in_sizes, int n_in,
                              void* d_out, int out_size, void* d_ws, size_t ws_size,
                              hipStream_t stream) {
    const int*   chars = (const int*)d_in[0];
    const float* emb   = (const float*)d_in[1];
    const float* w1    = (const float*)d_in[2];
    const float* b1    = (const float*)d_in[3];
    const float* w3    = (const float*)d_in[4];
    const float* b3    = (const float*)d_in[5];
    const float* w5    = (const float*)d_in[6];
    const float* b5    = (const float*)d_in[7];
    const float* lw    = (const float*)d_in[8];
    const float* lb    = (const float*)d_in[9];

    // ws: P5f [256][2304] f32 (2.36MB) | wTp [64][2304] f32 (0.59MB)
    //   | outs [8192][768] bf16 (12.6MB) | lwb [256][768] bf16 (0.39MB)
    float*  P5f  = (float*)d_ws;
    float*  wTp  = P5f + VOCAB * UNITF;
    ushort* outs = (ushort*)(wTp + EE * UNITF);
    ushort* lwb  = outs + (size_t)NW * K3;

    prep<<<768, 256, 0, stream>>>(w1, w3, w5, lw, wTp, lwb);
    build_tables<<<dim3(VOCAB/4, 9), 256, 0, stream>>>(emb, wTp, P5f);
    conv_pool<<<dim3(NW/128, 64), 256, 0, stream>>>(chars, P5f, b1, b3, b5, outs);
    gemm_out<<<dim3(NW/32, HH/32), 64, 0, stream>>>(outs, lwb, lb, (float*)d_out);
}

// Round 13
// 131.327 us; speedup vs baseline: 1.0993x; 1.0993x over previous
//
#include <hip/hip_runtime.h>
#include <hip/hip_bf16.h>

#define WW 20
#define NW 8192         // 64*128 words
#define VOCAB 256
#define EE 64
#define HH 256
#define K3 768          // 3*HH
#define UNIT 2304       // ushorts per vocab unit (P5) = 4608 B

typedef short bf16x8 __attribute__((ext_vector_type(8)));
typedef float f32x4  __attribute__((ext_vector_type(4)));

__device__ __forceinline__ ushort f2bs(float x) {
    __hip_bfloat16 h = __float2bfloat16(x);
    union { __hip_bfloat16 h; ushort u; } c; c.h = h; return c.u;
}
__device__ __forceinline__ float blo(unsigned u) {
    union { unsigned i; float f; } c; c.i = u << 16; return c.f;
}
__device__ __forceinline__ float bhi(unsigned u) {
    union { unsigned i; float f; } c; c.i = u & 0xffff0000u; return c.f;
}
__device__ __forceinline__ unsigned pack2(float lo, float hi) {
    return (unsigned)f2bs(lo) | ((unsigned)f2bs(hi) << 16);
}

// sliding-window update for one h given this char's 9 bf16 taps.
// j compile-time (fully unrolled caller) so %3/%5 indices and guards fold.
#define STEP(j, qq, t8v, a3, a5, mm1, mm3, mm5) {                        \
    float t0 = blo((qq).x), t1 = bhi((qq).x);                            \
    float t2 = blo((qq).y), t3 = bhi((qq).y);                            \
    float t4 = blo((qq).z), t5 = bhi((qq).z);                            \
    float t6 = blo((qq).w), t7 = bhi((qq).w);                            \
    mm1 = fmaxf(mm1, t0);                                                \
    if ((j) + 1 < WW) a3[((j)+1)%3] = t1;                                \
    a3[(j)%3] += t2;                                                     \
    if ((j) >= 1) { a3[((j)-1)%3] += t3;                                 \
                    mm3 = fmaxf(mm3, a3[((j)-1)%3]); }                   \
    if ((j) + 2 < WW) a5[((j)+2)%5] = t4;                                \
    if ((j) + 1 < WW) a5[((j)+1)%5] += t5;                               \
    a5[(j)%5] += t6;                                                     \
    if ((j) >= 1) a5[((j)-1)%5] += t7;                                   \
    if ((j) >= 2) { a5[((j)-2)%5] += (t8v);                              \
                    mm5 = fmaxf(mm5, a5[((j)-2)%5]); }                   \
}

// ---------------------------------------------------------------------------
// P5 layout (per vocab v, 2304 ushorts = 4608 B): 32 slices s of 144 B:
//   [hl 0..7][taps 0..7] (8 x 16 B rows), then [tap8 for hl 0..7] (16 B).
//   j = s*72 + r;  r<64: tap=r&7, h=s*8+(r>>3);  r>=64: tap=8, h=s*8+(r-64).
// bf16 kept deliberately: R12's f32 table doubled staging+LDS traffic and
// produced 1.24e7 bank-conflict cycles (144-B f32 stride -> 8 bank classes).
// ---------------------------------------------------------------------------

// K0: prep. blocks 0..575: wTp[e][j] f32 (P5 column order);
//          blocks 576..767: lw f32 -> bf16.
__global__ __launch_bounds__(256) void prep(
        const float* __restrict__ w1,
        const float* __restrict__ w3,
        const float* __restrict__ w5,
        const float* __restrict__ lw,
        float* __restrict__ wTp,
        ushort* __restrict__ lwb) {
    const int bid = blockIdx.x;
    if (bid < 576) {
        int idx = bid * 256 + threadIdx.x;      // = e*2304 + j, 147456 total
        int e = idx / UNIT;
        int j = idx - e * UNIT;
        int s = j / 72, r = j - s * 72;
        int tap, h;
        if (r < 64) { tap = r & 7; h = s*8 + (r >> 3); }
        else        { tap = 8;     h = s*8 + (r - 64); }
        float v;
        if (tap == 0)      v = w1[h*EE + e];
        else if (tap <= 3) v = w3[(h*EE + e)*3 + (tap-1)];
        else               v = w5[(h*EE + e)*5 + (tap-4)];
        wTp[idx] = v;
    } else {
        int i = ((bid - 576) * 256 + threadIdx.x) * 4;
        float4 v = *(const float4*)(lw + i);
        ushort4 o4;
        o4.x = f2bs(v.x); o4.y = f2bs(v.y); o4.z = f2bs(v.z); o4.w = f2bs(v.w);
        *(ushort4*)(lwb + i) = o4;
    }
}

// K1: P5[v][j] = sum_e emb[v][e] * wTp[e][j]. 4 vocab rows per block,
// grid (64, 9) x 256 thr. Coalesced streaming reads/writes.
__global__ __launch_bounds__(256) void build_tables(
        const float* __restrict__ emb,
        const float* __restrict__ wTp,
        ushort* __restrict__ P5) {
    __shared__ float emb_s[4][EE];
    const int v0 = blockIdx.x * 4;
    const int j  = blockIdx.y * 256 + threadIdx.x;
    const int t  = threadIdx.x;
    emb_s[t >> 6][t & 63] = emb[v0*EE + t];
    __syncthreads();

    float a0 = 0.f, a1 = 0.f, a2 = 0.f, a3 = 0.f;
    const float* wp = wTp + j;
    #pragma unroll 8
    for (int e = 0; e < EE; ++e) {
        float w = wp[e * UNIT];
        a0 += emb_s[0][e] * w; a1 += emb_s[1][e] * w;
        a2 += emb_s[2][e] * w; a3 += emb_s[3][e] * w;
    }
    P5[(size_t)(v0+0)*UNIT + j] = f2bs(a0);
    P5[(size_t)(v0+1)*UNIT + j] = f2bs(a1);
    P5[(size_t)(v0+2)*UNIT + j] = f2bs(a2);
    P5[(size_t)(v0+3)*UNIT + j] = f2bs(a3);
}

// ---------------------------------------------------------------------------
// K2: conv+relu+maxpool, LDS-staged bf16 table (R11-proven inner loop).
// Block = (256 words, 8-h slice), grid (32, 32) = 1024 blocks = exactly
// 4 blocks/CU (LDS 36.9 KB only -- chars LDS stage dropped; each thread
// reads its word's 20 chars as 5 aligned int4 from L2). Thread = (word-lane
// wl0 = t>>2, hl-pair p = t&3): owns h0 = s*8+2p, h0+1; cc loop covers 4
// words per thread. Per char: 2 x ds_read_b128 + 1 x ds_read_b32.
// Staging halved vs R11: 36.9 KB x 1024 = 37.8 MB table traffic total.
// Bias after max; ReLU at the end; packed u32 stores (h0 even).
// ---------------------------------------------------------------------------
__global__ __launch_bounds__(256) void conv_pool(
        const int* __restrict__ chars,
        const ushort* __restrict__ P5,
        const float* __restrict__ b1,
        const float* __restrict__ b3,
        const float* __restrict__ b5,
        ushort* __restrict__ outs) {
    __shared__ uint4 tileq[2304];          // 36864 B table slice
    const int t = threadIdx.x;
    const int g = blockIdx.x;              // word group 0..31 (256 words)
    const int s = blockIdx.y;              // h slice   0..31

    {   // stage table slice: 2304 16-B chunks, 9 per thread (v = c/9, k = c%9)
        const char* src = (const char*)P5 + (size_t)s * 144;
        char* dst = (char*)tileq;
        #pragma unroll
        for (int i = 0; i < 9; ++i) {
            int c = i*256 + t;
            int v = c / 9, k = c - 9*v;
            *(uint4*)(dst + v*144 + k*16) =
                *(const uint4*)(src + (size_t)v*4608 + k*16);
        }
    }
    __syncthreads();

    const int p   = t & 3;                 // hl pair 0..3
    const int wl0 = t >> 2;                // word lane 0..63
    const char* tile = (const char*)tileq;
    const int h0  = s*8 + p*2;
    const float2 bb1 = *(const float2*)(b1 + h0);
    const float2 bb3 = *(const float2*)(b3 + h0);
    const float2 bb5 = *(const float2*)(b5 + h0);

    #pragma unroll
    for (int cc = 0; cc < 4; ++cc) {
        const int wl = cc*64 + wl0;
        const int n  = g*256 + wl;

        // this word's chars: 5 aligned int4 from global (L2-hot, 80 B)
        int cw[WW];
        {
            const int4* cp = (const int4*)(chars + n * WW);
            #pragma unroll
            for (int i = 0; i < 5; ++i) {
                int4 v = cp[i];
                cw[i*4+0] = v.x; cw[i*4+1] = v.y;
                cw[i*4+2] = v.z; cw[i*4+3] = v.w;
            }
        }

        float a3[2][3], a5[2][5], m1[2], m3[2], m5[2];
        #pragma unroll
        for (int i = 0; i < 2; ++i) {
            a3[i][0] = 0.f; a5[i][0] = 0.f; a5[i][1] = 0.f;
            m1[i] = -1e30f; m3[i] = -1e30f; m5[i] = -1e30f;
        }

        uint4 qa[2], qb[2]; unsigned t8[2];
        {   // preload char 0
            int c0 = cw[0];
            qa[0] = *(const uint4*)(tile + c0*144 + p*32);
            qb[0] = *(const uint4*)(tile + c0*144 + p*32 + 16);
            t8[0] = *(const unsigned*)(tile + c0*144 + 128 + p*4);
        }

        #pragma unroll
        for (int j = 0; j < WW; ++j) {
            const int cur = j & 1, nxt = cur ^ 1;
            if (j + 1 < WW) {               // prefetch char j+1
                int cn = cw[j+1];
                qa[nxt] = *(const uint4*)(tile + cn*144 + p*32);
                qb[nxt] = *(const uint4*)(tile + cn*144 + p*32 + 16);
                t8[nxt] = *(const unsigned*)(tile + cn*144 + 128 + p*4);
            }
            float t8lo = blo(t8[cur]), t8hi = bhi(t8[cur]);
            STEP(j, qa[cur], t8lo, a3[0], a5[0], m1[0], m3[0], m5[0]);
            STEP(j, qb[cur], t8hi, a3[1], a5[1], m1[1], m3[1], m5[1]);
        }
        #pragma unroll
        for (int i = 0; i < 2; ++i) {
            m3[i] = fmaxf(m3[i], a3[i][(WW-1)%3]);     // pos 19
            m5[i] = fmaxf(m5[i], a5[i][(WW-2)%5]);     // pos 18
            m5[i] = fmaxf(m5[i], a5[i][(WW-1)%5]);     // pos 19
        }

        unsigned* op = (unsigned*)(outs + (size_t)n * K3 + h0);
        op[0*(HH/2)] = pack2(fmaxf(m1[0]+bb1.x, 0.f), fmaxf(m1[1]+bb1.y, 0.f));
        op[1*(HH/2)] = pack2(fmaxf(m3[0]+bb3.x, 0.f), fmaxf(m3[1]+bb3.y, 0.f));
        op[2*(HH/2)] = pack2(fmaxf(m5[0]+bb5.x, 0.f), fmaxf(m5[1]+bb5.y, 0.f));
    }
}

// ---------------------------------------------------------------------------
// K3: out = outs @ lw^T + lb via MFMA 16x16x32. 32m x 32n per wave,
// grid (256, 8) = 2048 single-wave blocks. Double-buffered fragments,
// fully unrolled K.
// A[m][k]: m=lane&15, k=quad*8+j. B[k][n]=lw[n][k]: n=lane&15, k=quad*8+j.
// C/D: col=lane&15, row=quad*4+reg.
// ---------------------------------------------------------------------------
__global__ __launch_bounds__(64) void gemm_out(
        const ushort* __restrict__ outs,   // [8192][768] bf16
        const ushort* __restrict__ lwb,    // [256][768] bf16
        const float* __restrict__ lb,
        float* __restrict__ out) {
    const int lane = threadIdx.x;
    const int m0 = blockIdx.x * 32;
    const int n0 = blockIdx.y * 32;
    const int mrow = lane & 15, quad = lane >> 4;

    f32x4 acc00 = (f32x4){0,0,0,0}, acc01 = (f32x4){0,0,0,0};
    f32x4 acc10 = (f32x4){0,0,0,0}, acc11 = (f32x4){0,0,0,0};
    const ushort* ap = outs + (size_t)(m0 + mrow) * K3 + quad * 8;
    const ushort* bp = lwb  + (size_t)(n0 + mrow) * K3 + quad * 8;

    bf16x8 a0 = *(const bf16x8*)ap, a1 = *(const bf16x8*)(ap + 16*K3);
    bf16x8 b0 = *(const bf16x8*)bp, b1 = *(const bf16x8*)(bp + 16*K3);

    #pragma unroll
    for (int it = 0; it < K3/32; ++it) {
        const int kn = (it + 1 < K3/32) ? (it + 1) * 32 : 0;
        bf16x8 a0n = *(const bf16x8*)(ap + kn);
        bf16x8 a1n = *(const bf16x8*)(ap + 16*K3 + kn);
        bf16x8 b0n = *(const bf16x8*)(bp + kn);
        bf16x8 b1n = *(const bf16x8*)(bp + 16*K3 + kn);
        acc00 = __builtin_amdgcn_mfma_f32_16x16x32_bf16(a0, b0, acc00, 0, 0, 0);
        acc01 = __builtin_amdgcn_mfma_f32_16x16x32_bf16(a0, b1, acc01, 0, 0, 0);
        acc10 = __builtin_amdgcn_mfma_f32_16x16x32_bf16(a1, b0, acc10, 0, 0, 0);
        acc11 = __builtin_amdgcn_mfma_f32_16x16x32_bf16(a1, b1, acc11, 0, 0, 0);
        a0 = a0n; a1 = a1n; b0 = b0n; b1 = b1n;
    }

    #pragma unroll
    for (int i = 0; i < 2; ++i) {
        #pragma unroll
        for (int jn = 0; jn < 2; ++jn) {
            const f32x4 acc = (i==0) ? (jn==0 ? acc00 : acc01)
                                     : (jn==0 ? acc10 : acc11);
            int ncol = n0 + jn*16 + mrow;
            float lbv = lb[ncol];
            #pragma unroll
            for (int r = 0; r < 4; ++r)
                out[(size_t)(m0 + i*16 + quad*4 + r)*HH + ncol] = acc[r] + lbv;
        }
    }
}

// ---------------------------------------------------------------------------
extern "C" void kernel_launch(void* const* d_in, const int* in_sizes, int n_in,
                              void* d_out, int out_size, void* d_ws, size_t ws_size,
                              hipStream_t stream) {
    const int*   chars = (const int*)d_in[0];
    const float* emb   = (const float*)d_in[1];
    const float* w1    = (const float*)d_in[2];
    const float* b1    = (const float*)d_in[3];
    const float* w3    = (const float*)d_in[4];
    const float* b3    = (const float*)d_in[5];
    const float* w5    = (const float*)d_in[6];
    const float* b5    = (const float*)d_in[7];
    const float* lw    = (const float*)d_in[8];
    const float* lb    = (const float*)d_in[9];

    // ws: P5 [256][2304] bf16 (1.18MB) | wTp [64][2304] f32 (0.59MB)
    //   | outs [8192][768] bf16 (12.6MB) | lwb [256][768] bf16 (0.39MB)
    ushort* P5   = (ushort*)d_ws;
    float*  wTp  = (float*)(P5 + VOCAB * UNIT);
    ushort* outs = (ushort*)(wTp + EE * UNIT);
    ushort* lwb  = outs + (size_t)NW * K3;

    prep<<<768, 256, 0, stream>>>(w1, w3, w5, lw, wTp, lwb);
    build_tables<<<dim3(VOCAB/4, 9), 256, 0, stream>>>(emb, wTp, P5);
    conv_pool<<<dim3(NW/256, 32), 256, 0, stream>>>(chars, P5, b1, b3, b5, outs);
    gemm_out<<<dim3(NW/32, HH/32), 64, 0, stream>>>(outs, lwb, lb, (float*)d_out);
}